// Round 1
// baseline (529.145 us; speedup 1.0000x reference)
//
#include <hip/hip_runtime.h>
#include <cstdint>

#define HEXP 10.0f
#define HEPS 1e-8f

typedef __bf16 bf16x8 __attribute__((ext_vector_type(8)));
typedef float f32x4 __attribute__((ext_vector_type(4)));

__device__ __forceinline__ unsigned short f2bf(float f) {
  uint32_t u = __float_as_uint(f);
  uint32_t r = (u + 0x7fffu + ((u >> 16) & 1u)) >> 16;
  return (unsigned short)r;
}

__device__ __forceinline__ void gl_lds16(const void* g, void* l) {
  __builtin_amdgcn_global_load_lds(
      (const __attribute__((address_space(1))) void*)g,
      (__attribute__((address_space(3))) void*)l, 16, 0, 0);
}

// ---------------- row L2-normalize f32 -> bf16 (D must be 1024) ----------------
__global__ __launch_bounds__(256) void k_rownorm(const float* __restrict__ in,
                                                 unsigned short* __restrict__ out,
                                                 int D) {
  const int row = blockIdx.x;
  const int tid = threadIdx.x;
  const float4* inr = (const float4*)(in + (size_t)row * D);
  float4 v = inr[tid];
  float ss = v.x * v.x + v.y * v.y + v.z * v.z + v.w * v.w;
#pragma unroll
  for (int off = 32; off >= 1; off >>= 1) ss += __shfl_xor(ss, off, 64);
  __shared__ float s4[4];
  if ((tid & 63) == 0) s4[tid >> 6] = ss;
  __syncthreads();
  float tot = s4[0] + s4[1] + s4[2] + s4[3];
  float scale = 1.f / fmaxf(sqrtf(tot), 1e-12f);
  ushort4 o;
  o.x = f2bf(v.x * scale);
  o.y = f2bf(v.y * scale);
  o.z = f2bf(v.z * scale);
  o.w = f2bf(v.w * scale);
  ((ushort4*)(out + (size_t)row * D))[tid] = o;
}

// ------------- fused GEMM (xn . wn^T) + logits + per-tile online LSE -------------
// 128x128 tile, BK=32, 4 waves, 16x16x32 bf16 MFMA (m97 structure).
__global__ __launch_bounds__(256) void k_gemm_lse(
    const unsigned short* __restrict__ xnb,
    const unsigned short* __restrict__ wnb,
    const int* __restrict__ tgt,
    float2* __restrict__ parts,
    float* __restrict__ tlp,
    int M, int C, int D, int ntN) {
  __shared__ unsigned short sA[128 * 32];
  __shared__ unsigned short sB[128 * 32];
  __shared__ int s_tgt[128];

  const int ntM = M >> 7;
  const int bid = blockIdx.x;
  const int tileM = bid % ntM;
  const int tileN = bid / ntM;
  const int row0 = tileM << 7;
  const int c0 = tileN << 7;

  const int tid = threadIdx.x;
  const int lane = tid & 63;
  const int wid = tid >> 6;
  const int wr = wid >> 1, wc = wid & 1;
  const int fcol = lane & 15;  // fragment row/col within 16
  const int kq = lane >> 4;    // k-quarter 0..3

  if (tid < 128) s_tgt[tid] = tgt[row0 + tid];

  f32x4 acc[4][4];
#pragma unroll
  for (int m = 0; m < 4; ++m)
#pragma unroll
    for (int n = 0; n < 4; ++n) acc[m][n] = (f32x4){0.f, 0.f, 0.f, 0.f};

  // staging: tile = 128 rows x 32 k of bf16 = 8KB; 256 thr x 16B x 2 chunks
  const int e0 = tid * 8;
  const int r0s = e0 >> 5, c0s = e0 & 31;
  const int e1 = 2048 + tid * 8;
  const int r1s = e1 >> 5, c1s = e1 & 31;
  const size_t Dz = (size_t)D;

  const int nk = D >> 5;
  for (int kt = 0; kt < nk; ++kt) {
    const int k0 = kt << 5;
    __syncthreads();  // previous iter's LDS reads done
    gl_lds16(xnb + (size_t)(row0 + r0s) * Dz + k0 + c0s, &sA[wid * 512]);
    gl_lds16(wnb + (size_t)(c0 + r0s) * Dz + k0 + c0s, &sB[wid * 512]);
    gl_lds16(xnb + (size_t)(row0 + r1s) * Dz + k0 + c1s, &sA[2048 + wid * 512]);
    gl_lds16(wnb + (size_t)(c0 + r1s) * Dz + k0 + c1s, &sB[2048 + wid * 512]);
    __syncthreads();  // compiler drains vmcnt before barrier

    bf16x8 af[4], bfr[4];
#pragma unroll
    for (int m = 0; m < 4; ++m)
      af[m] = *(const bf16x8*)&sA[((wr << 6) + (m << 4) + fcol) * 32 + kq * 8];
#pragma unroll
    for (int n = 0; n < 4; ++n)
      bfr[n] = *(const bf16x8*)&sB[((wc << 6) + (n << 4) + fcol) * 32 + kq * 8];
#pragma unroll
    for (int m = 0; m < 4; ++m)
#pragma unroll
      for (int n = 0; n < 4; ++n)
        acc[m][n] =
            __builtin_amdgcn_mfma_f32_16x16x32_bf16(af[m], bfr[n], acc[m][n], 0, 0, 0);
  }

  // epilogue: lp = -10*log(sqrt(max(2-2s,0))+eps); per-row online (max,sumexp)
  // C/D layout (verified m89/m91): col = lane&15, row = (lane>>4)*4 + j
#pragma unroll
  for (int m = 0; m < 4; ++m) {
#pragma unroll
    for (int j = 0; j < 4; ++j) {
      const int rl = (wr << 6) + (m << 4) + kq * 4 + j;
      const int trow = s_tgt[rl];
      float lpv[4];
      float vmax = -3.4e38f;
#pragma unroll
      for (int n = 0; n < 4; ++n) {
        float s = acc[m][n][j];
        float d = sqrtf(fmaxf(2.f - 2.f * s, 0.f));
        float lp = -HEXP * logf(d + HEPS);
        lpv[n] = lp;
        vmax = fmaxf(vmax, lp);
        int col = c0 + (wc << 6) + (n << 4) + fcol;
        if (col == trow) tlp[row0 + rl] = lp;
      }
#pragma unroll
      for (int off = 8; off >= 1; off >>= 1)
        vmax = fmaxf(vmax, __shfl_xor(vmax, off, 64));
      float se = 0.f;
#pragma unroll
      for (int n = 0; n < 4; ++n) se += expf(lpv[n] - vmax);
#pragma unroll
      for (int off = 8; off >= 1; off >>= 1) se += __shfl_xor(se, off, 64);
      if (fcol == 0)
        parts[((size_t)(row0 + rl) * ntN + tileN) * 2 + wc] = make_float2(vmax, se);
    }
  }
}

// ---------------- per-row LSE over partials + per-row loss ----------------
__global__ __launch_bounds__(256) void k_combine(const float2* __restrict__ parts,
                                                 const float* __restrict__ tlp,
                                                 float* __restrict__ rloss, int P) {
  const int row = blockIdx.x;
  const int tid = threadIdx.x;
  const float2* p = parts + (size_t)row * P;
  float m = -3.4e38f;
  for (int i = tid; i < P; i += 256) m = fmaxf(m, p[i].x);
#pragma unroll
  for (int off = 32; off >= 1; off >>= 1) m = fmaxf(m, __shfl_xor(m, off, 64));
  __shared__ float sm[4];
  __shared__ float ssum[4];
  if ((tid & 63) == 0) sm[tid >> 6] = m;
  __syncthreads();
  m = fmaxf(fmaxf(sm[0], sm[1]), fmaxf(sm[2], sm[3]));
  float s = 0.f;
  for (int i = tid; i < P; i += 256) s += expf(p[i].x - m) * p[i].y;
#pragma unroll
  for (int off = 32; off >= 1; off >>= 1) s += __shfl_xor(s, off, 64);
  if ((tid & 63) == 0) ssum[tid >> 6] = s;
  __syncthreads();
  if (tid == 0) {
    float tot = ssum[0] + ssum[1] + ssum[2] + ssum[3];
    float lse = m + logf(tot);
    float pt = expf(tlp[row] - lse);
    rloss[row] = -logf(pt + 1e-8f);
  }
}

// ---------------- mean over rows ----------------
__global__ __launch_bounds__(256) void k_mean(const float* __restrict__ rloss,
                                              float* __restrict__ out, int B) {
  const int tid = threadIdx.x;
  double s = 0.0;
  for (int i = tid; i < B; i += 256) s += (double)rloss[i];
#pragma unroll
  for (int off = 32; off >= 1; off >>= 1) s += __shfl_xor(s, off, 64);
  __shared__ double sd[4];
  if ((tid & 63) == 0) sd[tid >> 6] = s;
  __syncthreads();
  if (tid == 0) out[0] = (float)((sd[0] + sd[1] + sd[2] + sd[3]) / (double)B);
}

extern "C" void kernel_launch(void* const* d_in, const int* in_sizes, int n_in,
                              void* d_out, int out_size, void* d_ws, size_t ws_size,
                              hipStream_t stream) {
  const float* x = (const float*)d_in[0];
  const float* w = (const float*)d_in[1];
  const int* tg = (const int*)d_in[2];
  const int B = in_sizes[2];
  const int D = in_sizes[0] / B;       // 1024
  const int C = in_sizes[1] / D;       // 32000
  const int ntN = C / 128;             // 250

  char* ws = (char*)d_ws;
  unsigned short* xnb = (unsigned short*)ws;                 // B*D bf16
  unsigned short* wnb = xnb + (size_t)B * D;                 // C*D bf16
  size_t off = ((size_t)B * D + (size_t)C * D) * sizeof(unsigned short);
  off = (off + 255) & ~(size_t)255;
  float2* parts = (float2*)(ws + off);                       // B * ntN * 2
  off += (size_t)B * ntN * 2 * sizeof(float2);
  float* tlp = (float*)(ws + off);                           // B
  off += (size_t)B * sizeof(float);
  float* rloss = (float*)(ws + off);                         // B

  k_rownorm<<<B, 256, 0, stream>>>(x, xnb, D);
  k_rownorm<<<C, 256, 0, stream>>>(w, wnb, D);
  k_gemm_lse<<<(B / 128) * ntN, 256, 0, stream>>>(xnb, wnb, tg, parts, tlp, B, C, D, ntN);
  k_combine<<<B, 256, 0, stream>>>(parts, tlp, rloss, ntN * 2);
  k_mean<<<1, 256, 0, stream>>>(rloss, (float*)d_out, B);
}

// Round 3
// 488.315 us; speedup vs baseline: 1.0836x; 1.0836x over previous
//
#include <hip/hip_runtime.h>
#include <cstdint>

#define HEXP 10.0f
#define HEPS 1e-8f
#define LN2 0.69314718056f
#define RLN2 1.44269504089f

// hardware transcendentals: v_log_f32 computes log2(x), v_exp_f32 computes 2^x
__device__ __forceinline__ float hw_log2(float x) { return __builtin_amdgcn_logf(x); }
__device__ __forceinline__ float hw_exp2(float x) { return __builtin_amdgcn_exp2f(x); }

typedef __bf16 bf16x8 __attribute__((ext_vector_type(8)));
typedef float f32x4 __attribute__((ext_vector_type(4)));

__device__ __forceinline__ unsigned short f2bf(float f) {
  uint32_t u = __float_as_uint(f);
  uint32_t r = (u + 0x7fffu + ((u >> 16) & 1u)) >> 16;
  return (unsigned short)r;
}

__device__ __forceinline__ void gl_lds16(const void* g, void* l) {
  __builtin_amdgcn_global_load_lds(
      (const __attribute__((address_space(1))) void*)g,
      (__attribute__((address_space(3))) void*)l, 16, 0, 0);
}

// ---------------- row L2-normalize f32 -> bf16 (D must be 1024) ----------------
__global__ __launch_bounds__(256) void k_rownorm(const float* __restrict__ in,
                                                 unsigned short* __restrict__ out,
                                                 int D) {
  const int row = blockIdx.x;
  const int tid = threadIdx.x;
  const float4* inr = (const float4*)(in + (size_t)row * D);
  float4 v = inr[tid];
  float ss = v.x * v.x + v.y * v.y + v.z * v.z + v.w * v.w;
#pragma unroll
  for (int off = 32; off >= 1; off >>= 1) ss += __shfl_xor(ss, off, 64);
  __shared__ float s4[4];
  if ((tid & 63) == 0) s4[tid >> 6] = ss;
  __syncthreads();
  float tot = s4[0] + s4[1] + s4[2] + s4[3];
  float scale = 1.f / fmaxf(sqrtf(tot), 1e-12f);
  ushort4 o;
  o.x = f2bf(v.x * scale);
  o.y = f2bf(v.y * scale);
  o.z = f2bf(v.z * scale);
  o.w = f2bf(v.w * scale);
  ((ushort4*)(out + (size_t)row * D))[tid] = o;
}

// ------------- fused GEMM (xn . wn^T) + logits + per-tile online LSE -------------
// 128x128 tile, BK=32, 4 waves, 16x16x32 bf16 MFMA (m97 structure).
__global__ __launch_bounds__(256) void k_gemm_lse(
    const unsigned short* __restrict__ xnb,
    const unsigned short* __restrict__ wnb,
    const int* __restrict__ tgt,
    float2* __restrict__ parts,
    float* __restrict__ tlp,
    int M, int C, int D, int ntN) {
  __shared__ unsigned short sA[128 * 32];
  __shared__ unsigned short sB[128 * 32];
  __shared__ int s_tgt[128];

  const int ntM = M >> 7;
  const int bid = blockIdx.x;
  const int tileM = bid % ntM;
  const int tileN = bid / ntM;
  const int row0 = tileM << 7;
  const int c0 = tileN << 7;

  const int tid = threadIdx.x;
  const int lane = tid & 63;
  const int wid = tid >> 6;
  const int wr = wid >> 1, wc = wid & 1;
  const int fcol = lane & 15;  // fragment row/col within 16
  const int kq = lane >> 4;    // k-quarter 0..3

  if (tid < 128) s_tgt[tid] = tgt[row0 + tid];

  f32x4 acc[4][4];
#pragma unroll
  for (int m = 0; m < 4; ++m)
#pragma unroll
    for (int n = 0; n < 4; ++n) acc[m][n] = (f32x4){0.f, 0.f, 0.f, 0.f};

  // staging: tile = 128 rows x 32 k of bf16 = 8KB; 256 thr x 16B x 2 chunks
  const int e0 = tid * 8;
  const int r0s = e0 >> 5, c0s = e0 & 31;
  const int e1 = 2048 + tid * 8;
  const int r1s = e1 >> 5, c1s = e1 & 31;
  const size_t Dz = (size_t)D;

  const int nk = D >> 5;
  for (int kt = 0; kt < nk; ++kt) {
    const int k0 = kt << 5;
    __syncthreads();  // previous iter's LDS reads done
    gl_lds16(xnb + (size_t)(row0 + r0s) * Dz + k0 + c0s, &sA[wid * 512]);
    gl_lds16(wnb + (size_t)(c0 + r0s) * Dz + k0 + c0s, &sB[wid * 512]);
    gl_lds16(xnb + (size_t)(row0 + r1s) * Dz + k0 + c1s, &sA[2048 + wid * 512]);
    gl_lds16(wnb + (size_t)(c0 + r1s) * Dz + k0 + c1s, &sB[2048 + wid * 512]);
    __syncthreads();  // compiler drains vmcnt before barrier

    bf16x8 af[4], bfr[4];
#pragma unroll
    for (int m = 0; m < 4; ++m)
      af[m] = *(const bf16x8*)&sA[((wr << 6) + (m << 4) + fcol) * 32 + kq * 8];
#pragma unroll
    for (int n = 0; n < 4; ++n)
      bfr[n] = *(const bf16x8*)&sB[((wc << 6) + (n << 4) + fcol) * 32 + kq * 8];
#pragma unroll
    for (int m = 0; m < 4; ++m)
#pragma unroll
      for (int n = 0; n < 4; ++n)
        acc[m][n] =
            __builtin_amdgcn_mfma_f32_16x16x32_bf16(af[m], bfr[n], acc[m][n], 0, 0, 0);
  }

  // epilogue: lp = -10*ln(sqrt(max(2-2s,0))+eps) = -10*ln2*log2(d+eps)
  // C/D layout (verified m89/m91): col = lane&15, row = (lane>>4)*4 + j
#pragma unroll
  for (int m = 0; m < 4; ++m) {
#pragma unroll
    for (int j = 0; j < 4; ++j) {
      const int rl = (wr << 6) + (m << 4) + kq * 4 + j;
      const int trow = s_tgt[rl];
      float lpv[4];
      float vmax = -3.4e38f;
#pragma unroll
      for (int n = 0; n < 4; ++n) {
        float s = acc[m][n][j];
        float d = sqrtf(fmaxf(2.f - 2.f * s, 0.f));
        float lp = (-HEXP * LN2) * hw_log2(d + HEPS);
        lpv[n] = lp;
        vmax = fmaxf(vmax, lp);
        int col = c0 + (wc << 6) + (n << 4) + fcol;
        if (col == trow) tlp[row0 + rl] = lp;
      }
#pragma unroll
      for (int off = 8; off >= 1; off >>= 1)
        vmax = fmaxf(vmax, __shfl_xor(vmax, off, 64));
      float se = 0.f;
#pragma unroll
      for (int n = 0; n < 4; ++n) se += hw_exp2((lpv[n] - vmax) * RLN2);
#pragma unroll
      for (int off = 8; off >= 1; off >>= 1) se += __shfl_xor(se, off, 64);
      if (fcol == 0)
        parts[((size_t)(row0 + rl) * ntN + tileN) * 2 + wc] = make_float2(vmax, se);
    }
  }
}

// ---------------- per-row LSE over partials + per-row loss ----------------
__global__ __launch_bounds__(256) void k_combine(const float2* __restrict__ parts,
                                                 const float* __restrict__ tlp,
                                                 float* __restrict__ rloss, int P) {
  const int row = blockIdx.x;
  const int tid = threadIdx.x;
  const float2* p = parts + (size_t)row * P;
  float m = -3.4e38f;
  for (int i = tid; i < P; i += 256) m = fmaxf(m, p[i].x);
#pragma unroll
  for (int off = 32; off >= 1; off >>= 1) m = fmaxf(m, __shfl_xor(m, off, 64));
  __shared__ float sm[4];
  __shared__ float ssum[4];
  if ((tid & 63) == 0) sm[tid >> 6] = m;
  __syncthreads();
  m = fmaxf(fmaxf(sm[0], sm[1]), fmaxf(sm[2], sm[3]));
  float s = 0.f;
  for (int i = tid; i < P; i += 256) s += hw_exp2((p[i].x - m) * RLN2) * p[i].y;
#pragma unroll
  for (int off = 32; off >= 1; off >>= 1) s += __shfl_xor(s, off, 64);
  if ((tid & 63) == 0) ssum[tid >> 6] = s;
  __syncthreads();
  if (tid == 0) {
    float tot = ssum[0] + ssum[1] + ssum[2] + ssum[3];
    float lse = m + hw_log2(tot) * LN2;
    float pt = hw_exp2((tlp[row] - lse) * RLN2);
    rloss[row] = -hw_log2(pt + 1e-8f) * LN2;
  }
}

// ---------------- mean over rows ----------------
__global__ __launch_bounds__(256) void k_mean(const float* __restrict__ rloss,
                                              float* __restrict__ out, int B) {
  const int tid = threadIdx.x;
  double s = 0.0;
  for (int i = tid; i < B; i += 256) s += (double)rloss[i];
#pragma unroll
  for (int off = 32; off >= 1; off >>= 1) s += __shfl_xor(s, off, 64);
  __shared__ double sd[4];
  if ((tid & 63) == 0) sd[tid >> 6] = s;
  __syncthreads();
  if (tid == 0) out[0] = (float)((sd[0] + sd[1] + sd[2] + sd[3]) / (double)B);
}

extern "C" void kernel_launch(void* const* d_in, const int* in_sizes, int n_in,
                              void* d_out, int out_size, void* d_ws, size_t ws_size,
                              hipStream_t stream) {
  const float* x = (const float*)d_in[0];
  const float* w = (const float*)d_in[1];
  const int* tg = (const int*)d_in[2];
  const int B = in_sizes[2];
  const int D = in_sizes[0] / B;       // 1024
  const int C = in_sizes[1] / D;       // 32000
  const int ntN = C / 128;             // 250

  char* ws = (char*)d_ws;
  unsigned short* xnb = (unsigned short*)ws;                 // B*D bf16
  unsigned short* wnb = xnb + (size_t)B * D;                 // C*D bf16
  size_t off = ((size_t)B * D + (size_t)C * D) * sizeof(unsigned short);
  off = (off + 255) & ~(size_t)255;
  float2* parts = (float2*)(ws + off);                       // B * ntN * 2
  off += (size_t)B * ntN * 2 * sizeof(float2);
  float* tlp = (float*)(ws + off);                           // B
  off += (size_t)B * sizeof(float);
  float* rloss = (float*)(ws + off);                         // B

  k_rownorm<<<B, 256, 0, stream>>>(x, xnb, D);
  k_rownorm<<<C, 256, 0, stream>>>(w, wnb, D);
  k_gemm_lse<<<(B / 128) * ntN, 256, 0, stream>>>(xnb, wnb, tg, parts, tlp, B, C, D, ntN);
  k_combine<<<B, 256, 0, stream>>>(parts, tlp, rloss, ntN * 2);
  k_mean<<<1, 256, 0, stream>>>(rloss, (float*)d_out, B);
}

// Round 4
// 442.284 us; speedup vs baseline: 1.1964x; 1.1041x over previous
//
#include <hip/hip_runtime.h>
#include <cstdint>

#define HEXP 10.0f
#define HEPS 1e-8f
#define LN2 0.69314718056f
#define RLN2 1.44269504089f

// hardware transcendentals: v_log_f32 computes log2(x), v_exp_f32 computes 2^x
__device__ __forceinline__ float hw_log2(float x) { return __builtin_amdgcn_logf(x); }
__device__ __forceinline__ float hw_exp2(float x) { return __builtin_amdgcn_exp2f(x); }

typedef __bf16 bf16x8 __attribute__((ext_vector_type(8)));
typedef float f32x4 __attribute__((ext_vector_type(4)));

__device__ __forceinline__ unsigned short f2bf(float f) {
  uint32_t u = __float_as_uint(f);
  uint32_t r = (u + 0x7fffu + ((u >> 16) & 1u)) >> 16;
  return (unsigned short)r;
}

__device__ __forceinline__ void gl_lds16(const void* g, void* l) {
  __builtin_amdgcn_global_load_lds(
      (const __attribute__((address_space(1))) void*)g,
      (__attribute__((address_space(3))) void*)l, 16, 0, 0);
}

// ---------------- row L2-normalize f32 -> bf16 (D = 1024) ----------------
__global__ __launch_bounds__(256) void k_rownorm(const float* __restrict__ in,
                                                 unsigned short* __restrict__ out,
                                                 int D) {
  const int row = blockIdx.x;
  const int tid = threadIdx.x;
  const float4* inr = (const float4*)(in + (size_t)row * D);
  float4 v = inr[tid];
  float ss = v.x * v.x + v.y * v.y + v.z * v.z + v.w * v.w;
#pragma unroll
  for (int off = 32; off >= 1; off >>= 1) ss += __shfl_xor(ss, off, 64);
  __shared__ float s4[4];
  if ((tid & 63) == 0) s4[tid >> 6] = ss;
  __syncthreads();
  float tot = s4[0] + s4[1] + s4[2] + s4[3];
  float scale = 1.f / fmaxf(sqrtf(tot), 1e-12f);
  ushort4 o;
  o.x = f2bf(v.x * scale);
  o.y = f2bf(v.y * scale);
  o.z = f2bf(v.z * scale);
  o.w = f2bf(v.w * scale);
  ((ushort4*)(out + (size_t)row * D))[tid] = o;
}

// ------------- fused GEMM (xn . wn^T) + logits + per-tile online LSE -------------
// 256x256 tile, BK=64, 8 waves (2M x 4N), double-buffered K-tiles (128 KiB LDS),
// XOR-swizzled LDS (linear dest + pre-swizzled global src + swizzled read slot).
__global__ __launch_bounds__(512, 2) void k_gemm_lse(
    const unsigned short* __restrict__ xnb,
    const unsigned short* __restrict__ wnb,
    const int* __restrict__ tgt,
    float2* __restrict__ parts,
    float* __restrict__ tlp,
    int M, int C, int D, int ntN) {
  __shared__ unsigned short sA[2][256 * 64];
  __shared__ unsigned short sB[2][256 * 64];
  __shared__ int s_tgt[256];

  const int ntM = M >> 8;               // 16
  const int nwg = ntM * ntN;            // 2000 (divisible by 8)
  const int orig = blockIdx.x;
  const int cpx = nwg >> 3;
  const int bid = (orig & 7) * cpx + (orig >> 3);   // bijective XCD swizzle
  const int tileM = bid % ntM;
  const int tileN = bid / ntM;
  const int row0 = tileM << 8;
  const int c0 = tileN << 8;

  const int tid = threadIdx.x;
  const int lane = tid & 63;
  const int wid = tid >> 6;
  const int wr = wid >> 2;              // 0..1 : M-half
  const int wc = wid & 3;               // 0..3 : N-quarter
  const int fcol = lane & 15;
  const int kq = lane >> 4;

  if (tid < 256) s_tgt[tid] = tgt[row0 + tid];

  // staging source precompute (inverse-swizzled source column, linear LDS dest)
  // round r: linear elem e = r*4096 + tid*8; row=e>>6; slin=(e>>3)&7;
  // src col = (slin ^ (row&7)) * 8
  int srow[4], scol[4];
#pragma unroll
  for (int r = 0; r < 4; ++r) {
    int e = r * 4096 + tid * 8;
    int rw = e >> 6;
    int sl = (e >> 3) & 7;
    srow[r] = rw;
    scol[r] = (sl ^ (rw & 7)) << 3;
  }
  const size_t Dz = (size_t)D;

  f32x4 acc[8][4];
#pragma unroll
  for (int m = 0; m < 8; ++m)
#pragma unroll
    for (int n = 0; n < 4; ++n) acc[m][n] = (f32x4){0.f, 0.f, 0.f, 0.f};

  // swizzled read slots: row&7 == fcol&7 for all fragment rows (row = base16k + fcol)
  const int slot0 = (kq) ^ (fcol & 7);        // K-subtile w=0
  const int slot1 = (4 + kq) ^ (fcol & 7);    // K-subtile w=1
  const int abase = (wr * 128 + fcol) * 64;
  const int bbase = (wc * 64 + fcol) * 64;

  const int NT = D >> 6;                // 16 K-tiles
  // prologue: stage K-tile 0 into dbuf 0
#pragma unroll
  for (int r = 0; r < 4; ++r) {
    gl_lds16(xnb + (size_t)(row0 + srow[r]) * Dz + scol[r], &sA[0][r * 4096 + wid * 512]);
    gl_lds16(wnb + (size_t)(c0 + srow[r]) * Dz + scol[r], &sB[0][r * 4096 + wid * 512]);
  }

  for (int t = 0; t < NT; ++t) {
    const int d = t & 1;
    // __syncthreads drains vmcnt(0): tile t (issued one K-tile ago) is landed,
    // and all waves finished reading dbuf d^1 -> safe to overwrite it.
    __syncthreads();
    if (t + 1 < NT) {
      const int k0 = (t + 1) << 6;
#pragma unroll
      for (int r = 0; r < 4; ++r) {
        gl_lds16(xnb + (size_t)(row0 + srow[r]) * Dz + k0 + scol[r],
                 &sA[d ^ 1][r * 4096 + wid * 512]);
        gl_lds16(wnb + (size_t)(c0 + srow[r]) * Dz + k0 + scol[r],
                 &sB[d ^ 1][r * 4096 + wid * 512]);
      }
    }
    const unsigned short* pA = sA[d];
    const unsigned short* pB = sB[d];

    // B fragments: 4 n x 2 ksub = 8 x ds_read_b128 (kept live across mh phases)
    bf16x8 bf[4][2];
#pragma unroll
    for (int n = 0; n < 4; ++n) {
      bf[n][0] = *(const bf16x8*)&pB[bbase + n * 1024 + slot0 * 8];
      bf[n][1] = *(const bf16x8*)&pB[bbase + n * 1024 + slot1 * 8];
    }
#pragma unroll
    for (int mh = 0; mh < 2; ++mh) {
      bf16x8 af[4][2];
#pragma unroll
      for (int mm = 0; mm < 4; ++mm) {
        af[mm][0] = *(const bf16x8*)&pA[abase + (mh * 4 + mm) * 1024 + slot0 * 8];
        af[mm][1] = *(const bf16x8*)&pA[abase + (mh * 4 + mm) * 1024 + slot1 * 8];
      }
      __builtin_amdgcn_s_setprio(1);
#pragma unroll
      for (int mm = 0; mm < 4; ++mm)
#pragma unroll
        for (int n = 0; n < 4; ++n) {
          acc[mh * 4 + mm][n] = __builtin_amdgcn_mfma_f32_16x16x32_bf16(
              af[mm][0], bf[n][0], acc[mh * 4 + mm][n], 0, 0, 0);
          acc[mh * 4 + mm][n] = __builtin_amdgcn_mfma_f32_16x16x32_bf16(
              af[mm][1], bf[n][1], acc[mh * 4 + mm][n], 0, 0, 0);
        }
      __builtin_amdgcn_s_setprio(0);
    }
  }

  // epilogue: lp = -10*ln2*log2(sqrt(max(2-2s,0))+eps); per-row (max,sumexp) partials
  // C/D: col = lane&15 (fcol), row = kq*4 + j within each 16x16 fragment
#pragma unroll
  for (int m = 0; m < 8; ++m) {
#pragma unroll
    for (int j = 0; j < 4; ++j) {
      const int rl = wr * 128 + m * 16 + kq * 4 + j;
      const int grow = row0 + rl;
      const int trow = s_tgt[rl];
      float lpv[4];
      float vmax = -3.4e38f;
#pragma unroll
      for (int n = 0; n < 4; ++n) {
        float s = acc[m][n][j];
        float dd = sqrtf(fmaxf(2.f - 2.f * s, 0.f));
        float lp = (-HEXP * LN2) * hw_log2(dd + HEPS);
        lpv[n] = lp;
        vmax = fmaxf(vmax, lp);
        int col = c0 + wc * 64 + n * 16 + fcol;
        if (col == trow) tlp[grow] = lp;
      }
#pragma unroll
      for (int off = 8; off >= 1; off >>= 1)
        vmax = fmaxf(vmax, __shfl_xor(vmax, off, 64));
      float se = 0.f;
#pragma unroll
      for (int n = 0; n < 4; ++n) se += hw_exp2((lpv[n] - vmax) * RLN2);
#pragma unroll
      for (int off = 8; off >= 1; off >>= 1) se += __shfl_xor(se, off, 64);
      if (fcol == 0)
        parts[(size_t)grow * (ntN * 4) + tileN * 4 + wc] = make_float2(vmax, se);
    }
  }
}

// ---------------- per-row LSE over partials + per-row loss ----------------
__global__ __launch_bounds__(256) void k_combine(const float2* __restrict__ parts,
                                                 const float* __restrict__ tlp,
                                                 float* __restrict__ rloss, int P) {
  const int row = blockIdx.x;
  const int tid = threadIdx.x;
  const float2* p = parts + (size_t)row * P;
  float m = -3.4e38f;
  for (int i = tid; i < P; i += 256) m = fmaxf(m, p[i].x);
#pragma unroll
  for (int off = 32; off >= 1; off >>= 1) m = fmaxf(m, __shfl_xor(m, off, 64));
  __shared__ float sm[4];
  __shared__ float ssum[4];
  if ((tid & 63) == 0) sm[tid >> 6] = m;
  __syncthreads();
  m = fmaxf(fmaxf(sm[0], sm[1]), fmaxf(sm[2], sm[3]));
  float s = 0.f;
  for (int i = tid; i < P; i += 256) s += hw_exp2((p[i].x - m) * RLN2) * p[i].y;
#pragma unroll
  for (int off = 32; off >= 1; off >>= 1) s += __shfl_xor(s, off, 64);
  if ((tid & 63) == 0) ssum[tid >> 6] = s;
  __syncthreads();
  if (tid == 0) {
    float tot = ssum[0] + ssum[1] + ssum[2] + ssum[3];
    float lse = m + hw_log2(tot) * LN2;
    float pt = hw_exp2((tlp[row] - lse) * RLN2);
    rloss[row] = -hw_log2(pt + 1e-8f) * LN2;
  }
}

// ---------------- mean over rows ----------------
__global__ __launch_bounds__(256) void k_mean(const float* __restrict__ rloss,
                                              float* __restrict__ out, int B) {
  const int tid = threadIdx.x;
  double s = 0.0;
  for (int i = tid; i < B; i += 256) s += (double)rloss[i];
#pragma unroll
  for (int off = 32; off >= 1; off >>= 1) s += __shfl_xor(s, off, 64);
  __shared__ double sd[4];
  if ((tid & 63) == 0) sd[tid >> 6] = s;
  __syncthreads();
  if (tid == 0) out[0] = (float)((sd[0] + sd[1] + sd[2] + sd[3]) / (double)B);
}

extern "C" void kernel_launch(void* const* d_in, const int* in_sizes, int n_in,
                              void* d_out, int out_size, void* d_ws, size_t ws_size,
                              hipStream_t stream) {
  const float* x = (const float*)d_in[0];
  const float* w = (const float*)d_in[1];
  const int* tg = (const int*)d_in[2];
  const int B = in_sizes[2];
  const int D = in_sizes[0] / B;       // 1024
  const int C = in_sizes[1] / D;       // 32000
  const int ntN = C / 256;             // 125

  char* ws = (char*)d_ws;
  unsigned short* xnb = (unsigned short*)ws;                 // B*D bf16
  unsigned short* wnb = xnb + (size_t)B * D;                 // C*D bf16
  size_t off = ((size_t)B * D + (size_t)C * D) * sizeof(unsigned short);
  off = (off + 255) & ~(size_t)255;
  float2* parts = (float2*)(ws + off);                       // B * ntN * 4
  off += (size_t)B * ntN * 4 * sizeof(float2);
  float* tlp = (float*)(ws + off);                           // B
  off += (size_t)B * sizeof(float);
  float* rloss = (float*)(ws + off);                         // B

  k_rownorm<<<B, 256, 0, stream>>>(x, xnb, D);
  k_rownorm<<<C, 256, 0, stream>>>(w, wnb, D);
  k_gemm_lse<<<(B / 256) * ntN, 512, 0, stream>>>(xnb, wnb, tg, parts, tlp, B, C, D, ntN);
  k_combine<<<B, 256, 0, stream>>>(parts, tlp, rloss, ntN * 4);
  k_mean<<<1, 256, 0, stream>>>(rloss, (float*)d_out, B);
}